// Round 10
// baseline (243.632 us; speedup 1.0000x reference)
//
#include <hip/hip_runtime.h>

typedef __attribute__((ext_vector_type(8))) __bf16 bf16x8;
typedef __attribute__((ext_vector_type(4))) float f32x4;
typedef __attribute__((ext_vector_type(8))) unsigned short ushort8;
typedef const __attribute__((address_space(1))) unsigned int gq_t;
typedef __attribute__((address_space(3))) unsigned int lq_t;

// RNE float -> bf16 (finite inputs)
__device__ __forceinline__ unsigned short f2bf(float f) {
  unsigned int u = __builtin_bit_cast(unsigned int, f);
  u += 0x7fffu + ((u >> 16) & 1u);
  return (unsigned short)(u >> 16);
}

// ---------------- convert x: fp32 [M*K] -> bf16 ----------------
__global__ void cvt_x_kernel(const float* __restrict__ x, ushort8* __restrict__ o, int n8) {
  int stride = gridDim.x * blockDim.x;
  for (int i = blockIdx.x * blockDim.x + threadIdx.x; i < n8; i += stride) {
    const float4* p = (const float4*)(x) + 2 * (size_t)i;
    float4 v0 = p[0], v1 = p[1];
    ushort8 r;
    r[0] = f2bf(v0.x); r[1] = f2bf(v0.y); r[2] = f2bf(v0.z); r[3] = f2bf(v0.w);
    r[4] = f2bf(v1.x); r[5] = f2bf(v1.y); r[6] = f2bf(v1.z); r[7] = f2bf(v1.w);
    o[i] = r;
  }
}

// ------- convert weight: fp32 [N][K] * scale[n] -> bf16 --------
__global__ void cvt_w_kernel(const float* __restrict__ w, const float* __restrict__ scale,
                             ushort8* __restrict__ o, int n8, int k8) {
  int stride = gridDim.x * blockDim.x;
  for (int i = blockIdx.x * blockDim.x + threadIdx.x; i < n8; i += stride) {
    float s = scale[i / k8];
    const float4* p = (const float4*)(w) + 2 * (size_t)i;
    float4 v0 = p[0], v1 = p[1];
    ushort8 r;
    r[0] = f2bf(v0.x * s); r[1] = f2bf(v0.y * s); r[2] = f2bf(v0.z * s); r[3] = f2bf(v0.w * s);
    r[4] = f2bf(v1.x * s); r[5] = f2bf(v1.y * s); r[6] = f2bf(v1.z * s); r[7] = f2bf(v1.w * s);
    o[i] = r;
  }
}

// ============ 256x256 GEMM, 4 regions/K-tile, MFMA/mem interleaved ============
// C = A * B^T + bias.  A: bf16 [M][K], B: bf16 [N][K], C: fp32 [M][N].
// 8 waves (2 wr x 4 wc), BK=64, 128 KiB dynamic LDS.
//   buffer (64 KiB): [Amh0 16K][Amh1 16K][Bnh0 16K][Bnh1 16K], tile parity picks buffer.
// Each region = post-barrier; QUAD split into TWO 8-MFMA setprio chunks with the
// region's ds_reads / DMA-stage GLs woven BETWEEN chunks so the LDS+VMEM pipes run
// during the MFMA window (R5-R8 showed LDS and MFMA were ~serial: 42% MfmaUtil).
// Reads are issue-ordered to match k-outer consumption (shallow partial lgkm waits).
//
// Regions (tile t, cur = buffer(t&1), oth = other):
//  A1: Q8(mh0,bg0,k0); LDB1(cur)->bg1; GL aP1(t+1)->oth.Amh1; Q8(mh0,bg0,k1); Wa; B
//  A2: Q8(mh0,bg1,k0); GL aP0(t+2)->cur.Amh0; Q8(mh0,bg1,k1); LDA(cur,1)->af; B
//  A3: Q8(mh1,bg1,k0); GL bP1(t+2)->cur.Bnh1; Q8(mh1,bg1,k1); Wb; B
//  A4: Q8(mh1,bg0,k0); Q8(mh1,bg0,k1); LDB0(oth)->bg0(t+1); LDA(oth,0)->af(t+1);
//      GL bP0(t+2)->cur.Bnh0; B
// Overwrite audit (every GL target's prior LDS-read executed >=2 barriers earlier):
//  aP1->oth.Amh1: read LDA(cur,1)@A2(t-1), exec by A3(t-1); GL@A1(t): gap B3,B4,B1.
//  aP0->cur.Amh0: read LDA(oth,0)@A4(t-1), exec by B1(t); GL after B2(t).
//  bP1->cur.Bnh1: read LDB1@A1(t), exec by B2(t); GL after B3(t).
//  bP0->cur.Bnh0: read LDB0@A4(t-1), exec by B1(t); GL@A4(t): 3 barriers later.
// Register hazards: LDB1 overwrites bg1 (dead since A3(t-1)); LDB0/LDA(oth,0) after
// both A4 chunks (last bg0/af uses); LDA(cur,1) after both af(mh0) uses (A2 k1).
// vmcnt FIFO (2 loads/unit; per tile issue: aP1@A1, aP0@A2, bP1@A3, bP0@A4):
//  Wa (end A1): retire aP1(t); outstanding after = {aP0(t+1),bP1(t+1),bP0(t+1),
//    aP1(t+1)} = 8 -> vmcnt(8).  [t==NT-1 -> vmcnt(0), retires aP1(NT-1)]
//  Wb (end A3): retire {aP0(t+1),bP1(t+1),bP0(t+1)} (read @A4(t)/A1(t+1));
//    outstanding after = {aP1(t+1),aP0(t+2),bP1(t+2)} = 6 -> vmcnt(6).
//    [t==NT-2 -> vmcnt(2) (leaves aP1(NT-1)); t==NT-1 -> vmcnt(0)]
//  Cross-wave visibility: every unit is retired by ALL waves' Wa/Wb before the
//  barrier that precedes its first ds_read (LDA(cur,1) after B2>=Wa; LDB0/LDA(oth,0)
//  after B4>=Wb; A1 reads after B1>=Wb(t-1)).
// XOR swizzle byte ^= ((row&7)<<4): pre-swizzled global source + swizzled reads.
// global_load_lds offset immediate applies to LDS dest too -> ALWAYS offset=0;
// K-advance in 8 running pointers (pre-led: aP1 +1 tile; aP0/bP1/bP0 +2 tiles).

#define BARRIER asm volatile("s_barrier" ::: "memory")
#define WAITV8 asm volatile("s_waitcnt vmcnt(8)" ::: "memory")
#define WAITV6 asm volatile("s_waitcnt vmcnt(6)" ::: "memory")
#define WAITV2 asm volatile("s_waitcnt vmcnt(2)" ::: "memory")
#define WAITV0 asm volatile("s_waitcnt vmcnt(0)" ::: "memory")
#define GL(p, d) __builtin_amdgcn_global_load_lds((gq_t*)(p), (lq_t*)(d), 16, 0, 0)

// 8 MFMA: fixed k, all (mm,nn); independent acc chains
#define Q8(MH, BG, NHB, KK)                                                              \
  do {                                                                                   \
    __builtin_amdgcn_s_setprio(1);                                                       \
    _Pragma("unroll") for (int mm = 0; mm < 4; ++mm) {                                   \
      _Pragma("unroll") for (int nn = 0; nn < 2; ++nn) {                                 \
        acc[(MH)*4 + mm][(NHB)*2 + nn] = __builtin_amdgcn_mfma_f32_16x16x32_bf16(        \
            af[mm][KK], BG[nn][KK], acc[(MH)*4 + mm][(NHB)*2 + nn], 0, 0, 0);            \
      }                                                                                  \
    }                                                                                    \
    __builtin_amdgcn_s_setprio(0);                                                       \
  } while (0)

#define TILE_BODY(T, CB)                                                                 \
  do {                                                                                   \
    const int t_ = (T);                                                                  \
    char* cur = lds + (CB) * 65536;                                                      \
    char* oth = lds + (((CB) ^ 1)) * 65536;                                              \
    /* A1 */                                                                             \
    Q8(0, bg0, 0, 0);                                                                    \
    LDB1(cur);                                                                           \
    if (t_ + 1 < NT) { GL(aP1lo, oth + 16384 + dstT);                                    \
                       GL(aP1hi, oth + 16384 + 8192 + dstT); }                           \
    Q8(0, bg0, 0, 1);                                                                    \
    if (t_ == NT - 1) { WAITV0; } else { WAITV8; }                                       \
    BARRIER;                                                                             \
    /* A2 */                                                                             \
    Q8(0, bg1, 1, 0);                                                                    \
    if (t_ + 2 < NT) { GL(aP0lo, cur + dstT);                                            \
                       GL(aP0hi, cur + 8192 + dstT); }                                   \
    Q8(0, bg1, 1, 1);                                                                    \
    LDA(cur, 1);                                                                         \
    BARRIER;                                                                             \
    /* A3 */                                                                             \
    Q8(1, bg1, 1, 0);                                                                    \
    if (t_ + 2 < NT) { GL(bP1lo, cur + 49152 + dstT);                                    \
                       GL(bP1hi, cur + 49152 + 8192 + dstT); }                           \
    Q8(1, bg1, 1, 1);                                                                    \
    if (t_ < NT - 2) { WAITV6; } else if (t_ == NT - 2) { WAITV2; } else { WAITV0; }     \
    BARRIER;                                                                             \
    /* A4 */                                                                             \
    Q8(1, bg0, 0, 0);                                                                    \
    Q8(1, bg0, 0, 1);                                                                    \
    if (t_ + 1 < NT) { LDB0(oth); LDA(oth, 0); }                                         \
    if (t_ + 2 < NT) { GL(bP0lo, cur + 32768 + dstT);                                    \
                       GL(bP0hi, cur + 32768 + 8192 + dstT); }                           \
    BARRIER;                                                                             \
    aP0lo += 64; aP0hi += 64; aP1lo += 64; aP1hi += 64;                                  \
    bP0lo += 64; bP0hi += 64; bP1lo += 64; bP1hi += 64;                                  \
  } while (0)

__global__ __launch_bounds__(512, 2) void gemm256_8ph(
    const unsigned short* __restrict__ A, const unsigned short* __restrict__ B,
    const float* __restrict__ bias, float* __restrict__ C, int M, int N, int K) {
  extern __shared__ char lds[];

  const int nbn = N >> 8;
  const int nwg = (M >> 8) * nbn;
  int bid = blockIdx.x;
  if ((nwg & 7) == 0) {  // XCD-aware swizzle (bijective when nwg%8==0)
    int q = nwg >> 3;
    bid = (bid & 7) * q + (bid >> 3);
  }
  const int bm = (bid / nbn) << 8;
  const int bn = (bid % nbn) << 8;

  const int tid = threadIdx.x;
  const int lane = tid & 63;
  const int wid = tid >> 6;
  const int wr = wid >> 2;  // 0..1
  const int wc = wid & 3;   // 0..3
  const int NT = K >> 6;    // K-tiles of 64
  const int dstT = tid * 16;

  // ---- pre-swizzled global sources (rule 21: linear LDS dest + inv-swz source) ----
  const int colel = (((tid & 7) ^ ((tid >> 3) & 7)) << 3);
  const unsigned short* aBase = A + (size_t)(bm + (tid >> 3)) * K + colel;
  const unsigned short* bBase = B + (size_t)(bn + ((tid >> 8) << 6) + ((tid >> 3) & 31)) * K + colel;
  const unsigned short* aP0lo = aBase;                    // Amh0 rows 0-63
  const unsigned short* aP0hi = aBase + (size_t)128 * K;  // Amh0 rows 128-191
  const unsigned short* aP1lo = aBase + (size_t)64 * K;   // Amh1 rows 64-127
  const unsigned short* aP1hi = aBase + (size_t)192 * K;  // Amh1 rows 192-255
  const unsigned short* bP0lo = bBase;                    // Bnh0
  const unsigned short* bP0hi = bBase + (size_t)128 * K;
  const unsigned short* bP1lo = bBase + (size_t)32 * K;   // Bnh1
  const unsigned short* bP1hi = bBase + (size_t)160 * K;

  // ---- fragment read offsets (swizzled) ----
  const int i15 = lane & 15;
  const int qg = lane >> 4;
  const int swz = (lane & 7) << 4;
  const int colp0 = (qg << 4) ^ swz;
  const int colp1 = ((qg << 4) | 64) ^ swz;
  const int aoff = wr * 8192 + i15 * 128;
  const int boff = 32768 + wc * 4096 + i15 * 128;

  f32x4 acc[8][4];
#pragma unroll
  for (int m = 0; m < 8; ++m)
#pragma unroll
    for (int n = 0; n < 4; ++n) acc[m][n] = (f32x4){0.f, 0.f, 0.f, 0.f};

  bf16x8 af[4][2];   // current A half [mm][kk]
  bf16x8 bg0[2][2];  // Bnh0 fragments (loaded one region early)
  bf16x8 bg1[2][2];  // Bnh1 fragments

  // reads issue-ordered k-outer to match Q8 consumption (shallow lgkm waits)
  auto LDA = [&](const char* base, int mh) {
    const char* p = base + mh * 16384 + aoff;
#pragma unroll
    for (int kk = 0; kk < 2; ++kk)
#pragma unroll
      for (int mm = 0; mm < 4; ++mm)
        af[mm][kk] = *(const bf16x8*)(p + mm * 2048 + (kk ? colp1 : colp0));
  };
  auto LDB0 = [&](const char* base) {
    const char* p = base + boff;
#pragma unroll
    for (int kk = 0; kk < 2; ++kk)
#pragma unroll
      for (int nn = 0; nn < 2; ++nn)
        bg0[nn][kk] = *(const bf16x8*)(p + nn * 2048 + (kk ? colp1 : colp0));
  };
  auto LDB1 = [&](const char* base) {
    const char* p = base + 16384 + boff;
#pragma unroll
    for (int kk = 0; kk < 2; ++kk)
#pragma unroll
      for (int nn = 0; nn < 2; ++nn)
        bg1[nn][kk] = *(const bf16x8*)(p + nn * 2048 + (kk ? colp1 : colp0));
  };

  // ---- prologue ----
  // FIFO: [aP0(0), bP0(0), bP1(0)] retired; keep [aP1(0), aP0(1), bP1(1), bP0(1)] = 8.
  GL(aP0lo, lds + dstT);                      GL(aP0hi, lds + 8192 + dstT);
  GL(bP0lo, lds + 32768 + dstT);              GL(bP0hi, lds + 32768 + 8192 + dstT);
  GL(bP1lo, lds + 49152 + dstT);              GL(bP1hi, lds + 49152 + 8192 + dstT);
  GL(aP1lo, lds + 16384 + dstT);              GL(aP1hi, lds + 16384 + 8192 + dstT);
  GL(aP0lo + 64, lds + 65536 + dstT);         GL(aP0hi + 64, lds + 65536 + 8192 + dstT);
  GL(bP1lo + 64, lds + 65536 + 49152 + dstT);
  GL(bP1hi + 64, lds + 65536 + 49152 + 8192 + dstT);
  GL(bP0lo + 64, lds + 65536 + 32768 + dstT);
  GL(bP0hi + 64, lds + 65536 + 32768 + 8192 + dstT);
  WAITV8;   // retire {Amh0,Bnh0,Bnh1}(0); keep 4 units (8 loads) in flight
  BARRIER;  // retired stages visible to all waves  (= B1 of tile 0)
  LDA(lds, 0);  // af  <- Amh0(0)
  LDB0(lds);    // bg0 <- Bnh0(0)
  // leads: aP1 stages (t+1) at A1 -> +64; aP0/bP1/bP0 stage (t+2) -> +128
  aP1lo += 64;  aP1hi += 64;
  aP0lo += 128; aP0hi += 128; bP1lo += 128; bP1hi += 128; bP0lo += 128; bP0hi += 128;

  // ---- main loop: 2 tiles per iteration (compile-time buffer parity) ----
  for (int t = 0; t < NT; t += 2) {
    TILE_BODY(t, 0);
    TILE_BODY(t + 1, 1);
  }

  // ---- epilogue: C/D map col=lane&15, row=(lane>>4)*4+reg ----
  const int r0 = bm + wr * 128 + ((lane >> 4) << 2);
  const int c0 = bn + wc * 64 + (lane & 15);
  float bv[4];
#pragma unroll
  for (int n = 0; n < 4; ++n) bv[n] = bias[c0 + n * 16];
#pragma unroll
  for (int m = 0; m < 8; ++m) {
#pragma unroll
    for (int r = 0; r < 4; ++r) {
      float* crow = C + (size_t)(r0 + m * 16 + r) * N + c0;
#pragma unroll
      for (int n = 0; n < 4; ++n) crow[n * 16] = acc[m][n][r] + bv[n];
    }
  }
}

// ---------- fallback: fp32 tiled (odd shapes / tiny ws) ----------
__global__ void gemm_fallback_kernel(const float* __restrict__ X, const float* __restrict__ W,
                                     const float* __restrict__ scale, const float* __restrict__ bias,
                                     float* __restrict__ out, int M, int N, int K) {
  __shared__ float as[64][33];
  __shared__ float bs[64][33];
  int tx = threadIdx.x & 15, ty = threadIdx.x >> 4;
  int brow = blockIdx.y * 64, bcol = blockIdx.x * 64;
  float acc[4][4] = {};
  for (int k0 = 0; k0 < K; k0 += 32) {
    int kw = (K - k0 < 32) ? (K - k0) : 32;
    for (int i = 0; i < 8; ++i) {
      int idx = (int)threadIdx.x + i * 256;
      int r = idx >> 5, c = idx & 31;
      int ga = brow + r, gb = bcol + r;
      as[r][c] = (ga < M && c < kw) ? X[(size_t)ga * K + k0 + c] : 0.f;
      bs[r][c] = (gb < N && c < kw) ? W[(size_t)gb * K + k0 + c] * scale[gb] : 0.f;
    }
    __syncthreads();
    for (int k = 0; k < 32; ++k)
#pragma unroll
      for (int i = 0; i < 4; ++i)
#pragma unroll
        for (int j = 0; j < 4; ++j)
          acc[i][j] += as[ty * 4 + i][k] * bs[tx * 4 + j][k];
    __syncthreads();
  }
  for (int i = 0; i < 4; ++i) {
    int r = brow + ty * 4 + i;
    if (r >= M) continue;
    for (int j = 0; j < 4; ++j) {
      int c = bcol + tx * 4 + j;
      if (c < N) out[(size_t)r * N + c] = acc[i][j] + bias[c];
    }
  }
}

extern "C" void kernel_launch(void* const* d_in, const int* in_sizes, int n_in,
                              void* d_out, int out_size, void* d_ws, size_t ws_size,
                              hipStream_t stream) {
  const float* x     = (const float*)d_in[0];
  const float* w     = (const float*)d_in[1];
  const float* scale = (const float*)d_in[2];
  const float* bias  = (const float*)d_in[3];
  float* out = (float*)d_out;

  const long N = in_sizes[2];            // D_OUT
  const long K = in_sizes[1] / N;        // D_IN
  const long M = (long)in_sizes[0] / K;  // B*S

  const size_t need = ((size_t)M * K + (size_t)N * K) * sizeof(unsigned short);
  const long NT = K / 64;
  const bool ok = (ws_size >= need) && (M % 256 == 0) && (N % 256 == 0) &&
                  (K % 128 == 0) && (NT >= 4);

  if (ok) {
    unsigned short* xa = (unsigned short*)d_ws;
    unsigned short* wb = xa + (size_t)M * K;
    cvt_x_kernel<<<2048, 256, 0, stream>>>(x, (ushort8*)xa, (int)((size_t)M * K / 8));
    cvt_w_kernel<<<1024, 256, 0, stream>>>(w, scale, (ushort8*)wb, (int)((size_t)N * K / 8), (int)(K / 8));

    (void)hipFuncSetAttribute((const void*)gemm256_8ph,
                              hipFuncAttributeMaxDynamicSharedMemorySize, 131072);
    int nwg = (int)((M / 256) * (N / 256));
    gemm256_8ph<<<nwg, 512, 131072, stream>>>(xa, wb, bias, out, (int)M, (int)N, (int)K);
  } else {
    dim3 grid((unsigned)((N + 63) / 64), (unsigned)((M + 63) / 64));
    gemm_fallback_kernel<<<grid, 256, 0, stream>>>(x, w, scale, bias, out, (int)M, (int)N, (int)K);
  }
}

// Round 11
// 164.638 us; speedup vs baseline: 1.4798x; 1.4798x over previous
//
#include <hip/hip_runtime.h>

typedef __attribute__((ext_vector_type(8))) __bf16 bf16x8;
typedef __attribute__((ext_vector_type(4))) float f32x4;
typedef __attribute__((ext_vector_type(8))) unsigned short ushort8;
typedef const __attribute__((address_space(1))) unsigned int gq_t;
typedef __attribute__((address_space(3))) unsigned int lq_t;

// RNE float -> bf16 (finite inputs)
__device__ __forceinline__ unsigned short f2bf(float f) {
  unsigned int u = __builtin_bit_cast(unsigned int, f);
  u += 0x7fffu + ((u >> 16) & 1u);
  return (unsigned short)(u >> 16);
}

// ------- fused convert: x -> bf16 and weight*scale -> bf16, one dispatch -------
__global__ void cvt_xw_kernel(const float* __restrict__ x, const float* __restrict__ w,
                              const float* __restrict__ scale,
                              ushort8* __restrict__ xa, ushort8* __restrict__ wb,
                              int n8x, int n8w, int k8) {
  int stride = gridDim.x * blockDim.x;
  int total = n8x + n8w;
  for (int i = blockIdx.x * blockDim.x + threadIdx.x; i < total; i += stride) {
    if (i < n8x) {
      const float4* p = (const float4*)(x) + 2 * (size_t)i;
      float4 v0 = p[0], v1 = p[1];
      ushort8 r;
      r[0] = f2bf(v0.x); r[1] = f2bf(v0.y); r[2] = f2bf(v0.z); r[3] = f2bf(v0.w);
      r[4] = f2bf(v1.x); r[5] = f2bf(v1.y); r[6] = f2bf(v1.z); r[7] = f2bf(v1.w);
      xa[i] = r;
    } else {
      int j = i - n8x;
      float s = scale[j / k8];
      const float4* p = (const float4*)(w) + 2 * (size_t)j;
      float4 v0 = p[0], v1 = p[1];
      ushort8 r;
      r[0] = f2bf(v0.x * s); r[1] = f2bf(v0.y * s); r[2] = f2bf(v0.z * s); r[3] = f2bf(v0.w * s);
      r[4] = f2bf(v1.x * s); r[5] = f2bf(v1.y * s); r[6] = f2bf(v1.z * s); r[7] = f2bf(v1.w * s);
      wb[j] = r;
    }
  }
}

// =================== 256x256 4-barrier/K-tile GEMM (R6 winner) ===================
// C = A * B^T + bias.  A: bf16 [M][K], B: bf16 [N][K], C: fp32 [M][N].
// 8 waves (2 wr x 4 wc), BK=64, 128 KiB dynamic LDS.
//   buffer (64 KiB): [Amh0 16K][Amh1 16K][Bnh0 16K][Bnh1 16K], tile parity picks buffer.
// ONE barrier per phase (between {ds_reads, GL stage} and QUAD) — no end-of-phase
// barrier, so waves STAGGER: after QUAD(P-1) a wave immediately issues P's
// reads/stage while slower waves still feed the MFMA pipe. Measured best of the
// R1-R9 schedule family (139.4us GEMM, MfmaUtil 43, conflicts 0).
// Deadness audit (4-barrier scheme): each staged region's old readers lgkm-complete
// >=1 full phase + barrier before the overwriting GL issues:
//   P1->ob.Bnh0 (old read t-2.P4-tail), P2->ob.Amh1 (old read t-1.P3),
//   P3->cb.Amh0 (old read t.P1), P4->cb.Bnh1 (old read t.P2).
// vmcnt ledger (FIFO, 2 loads/unit): WAITV4 at P4 retires exactly tile t+1's 4
// units (wait distance 3-4 phases, zero-stall per R8 depth-3 null); WAITV0 at NT-2.
// XOR swizzle byte ^= ((row&7)<<4): pre-swizzled global source + swizzled reads.
// global_load_lds offset immediate applies to LDS dest too -> ALWAYS offset=0;
// K-advance lives in 8 running pointers (pre-led 1 or 2 tiles), +64 elems/tile.

#define BARRIER asm volatile("s_barrier" ::: "memory")
#define WAITV4 asm volatile("s_waitcnt vmcnt(4)" ::: "memory")
#define WAITV0 asm volatile("s_waitcnt vmcnt(0)" ::: "memory")
#define GL(p, d) __builtin_amdgcn_global_load_lds((gq_t*)(p), (lq_t*)(d), 16, 0, 0)

#define QUAD(MH, BG, NHB)                                                                \
  do {                                                                                   \
    __builtin_amdgcn_s_setprio(1);                                                       \
    _Pragma("unroll") for (int k_ = 0; k_ < 2; ++k_) {                                   \
      _Pragma("unroll") for (int mm = 0; mm < 4; ++mm) {                                 \
        _Pragma("unroll") for (int nn = 0; nn < 2; ++nn) {                               \
          acc[(MH)*4 + mm][(NHB)*2 + nn] = __builtin_amdgcn_mfma_f32_16x16x32_bf16(      \
              af[mm][k_], BG[nn][k_], acc[(MH)*4 + mm][(NHB)*2 + nn], 0, 0, 0);          \
        }                                                                                \
      }                                                                                  \
    }                                                                                    \
    __builtin_amdgcn_s_setprio(0);                                                       \
  } while (0)

#define TILE_BODY(T, CB)                                                                 \
  do {                                                                                   \
    const int t_ = (T);                                                                  \
    char* cur = lds + (CB) * 65536;                                                      \
    char* oth = lds + (((CB) ^ 1)) * 65536;                                              \
    /* P1: reads Amh0 (8 ds_read) ; stages Bn01(t+1) -> ob.Bnh0 */                       \
    LDA(cur, 0);                                                                         \
    if (t_ + 1 < NT) { GL(bP0lo, oth + 32768 + dstT);                                    \
                       GL(bP0hi, oth + 32768 + 8192 + dstT); }                           \
    BARRIER; QUAD(0, bg0, 0);                                                            \
    /* P2: reads Bnh1 (4) ; stages Am47(t+1) -> ob.Amh1 */                               \
    LDB1(cur);                                                                           \
    if (t_ + 1 < NT) { GL(aP1lo, oth + 16384 + dstT);                                    \
                       GL(aP1hi, oth + 16384 + 8192 + dstT); }                           \
    BARRIER; QUAD(0, bg1, 1);                                                            \
    /* P3: reads Amh1 (8) ; stages Am03(t+2) -> cb.Amh0 */                               \
    LDA(cur, 1);                                                                         \
    if (t_ + 2 < NT) { GL(aP0lo, cur + dstT);                                            \
                       GL(aP0hi, cur + 8192 + dstT); }                                   \
    BARRIER; QUAD(1, bg1, 1);                                                            \
    /* P4: stages Bn23(t+2) -> cb.Bnh1 ; wait ; BAR ; QUAD ; prefetch next Bnh0 (4) */   \
    if (t_ + 2 < NT) { GL(bP1lo, cur + 49152 + dstT);                                    \
                       GL(bP1hi, cur + 49152 + 8192 + dstT); }                           \
    if (t_ == NT - 2) { WAITV0; } else { WAITV4; }                                       \
    BARRIER; QUAD(1, bg0, 0);                                                            \
    if (t_ + 1 < NT) LDB0(oth);                                                          \
    aP0lo += 64; aP0hi += 64; aP1lo += 64; aP1hi += 64;                                  \
    bP0lo += 64; bP0hi += 64; bP1lo += 64; bP1hi += 64;                                  \
  } while (0)

__global__ __launch_bounds__(512, 2) void gemm256_8ph(
    const unsigned short* __restrict__ A, const unsigned short* __restrict__ B,
    const float* __restrict__ bias, float* __restrict__ C, int M, int N, int K) {
  extern __shared__ char lds[];

  const int nbn = N >> 8;
  const int nwg = (M >> 8) * nbn;
  int bid = blockIdx.x;
  if ((nwg & 7) == 0) {  // XCD-aware swizzle (bijective when nwg%8==0)
    int q = nwg >> 3;
    bid = (bid & 7) * q + (bid >> 3);
  }
  const int bm = (bid / nbn) << 8;
  const int bn = (bid % nbn) << 8;

  const int tid = threadIdx.x;
  const int lane = tid & 63;
  const int wid = tid >> 6;
  const int wr = wid >> 2;  // 0..1
  const int wc = wid & 3;   // 0..3
  const int NT = K >> 6;    // K-tiles of 64
  const int dstT = tid * 16;

  // ---- pre-swizzled global sources (rule 21: linear LDS dest + inv-swz source) ----
  // phys row within unit = tid>>3 ; logical col = ((tid&7) ^ ((tid>>3)&7)) * 8 elems
  const int colel = (((tid & 7) ^ ((tid >> 3) & 7)) << 3);
  const unsigned short* aBase = A + (size_t)(bm + (tid >> 3)) * K + colel;
  const unsigned short* bBase = B + (size_t)(bn + ((tid >> 8) << 6) + ((tid >> 3) & 31)) * K + colel;
  const unsigned short* aP0lo = aBase;                    // Amh0 rows 0-63
  const unsigned short* aP0hi = aBase + (size_t)128 * K;  // Amh0 rows 128-191
  const unsigned short* aP1lo = aBase + (size_t)64 * K;   // Amh1 rows 64-127
  const unsigned short* aP1hi = aBase + (size_t)192 * K;  // Amh1 rows 192-255
  const unsigned short* bP0lo = bBase;                    // Bnh0
  const unsigned short* bP0hi = bBase + (size_t)128 * K;
  const unsigned short* bP1lo = bBase + (size_t)32 * K;   // Bnh1
  const unsigned short* bP1hi = bBase + (size_t)160 * K;

  // ---- fragment read offsets (swizzled) ----
  const int i15 = lane & 15;
  const int qg = lane >> 4;
  const int swz = (lane & 7) << 4;
  const int colp0 = (qg << 4) ^ swz;
  const int colp1 = ((qg << 4) | 64) ^ swz;
  const int aoff = wr * 8192 + i15 * 128;
  const int boff = 32768 + wc * 4096 + i15 * 128;

  f32x4 acc[8][4];
#pragma unroll
  for (int m = 0; m < 8; ++m)
#pragma unroll
    for (int n = 0; n < 4; ++n) acc[m][n] = (f32x4){0.f, 0.f, 0.f, 0.f};

  bf16x8 af[4][2];   // current A half [mm][kk]
  bf16x8 bg0[2][2];  // Bnh0 fragments (prefetched one tile ahead)
  bf16x8 bg1[2][2];  // Bnh1 fragments (current tile)

  auto LDA = [&](const char* base, int mh) {
    const char* p = base + mh * 16384 + aoff;
#pragma unroll
    for (int mm = 0; mm < 4; ++mm) {
      af[mm][0] = *(const bf16x8*)(p + mm * 2048 + colp0);
      af[mm][1] = *(const bf16x8*)(p + mm * 2048 + colp1);
    }
  };
  auto LDB0 = [&](const char* base) {  // Bnh0 -> bg0
    const char* p = base + boff;
#pragma unroll
    for (int nn = 0; nn < 2; ++nn) {
      bg0[nn][0] = *(const bf16x8*)(p + nn * 2048 + colp0);
      bg0[nn][1] = *(const bf16x8*)(p + nn * 2048 + colp1);
    }
  };
  auto LDB1 = [&](const char* base) {  // Bnh1 -> bg1
    const char* p = base + 16384 + boff;
#pragma unroll
    for (int nn = 0; nn < 2; ++nn) {
      bg1[nn][0] = *(const bf16x8*)(p + nn * 2048 + colp0);
      bg1[nn][1] = *(const bf16x8*)(p + nn * 2048 + colp1);
    }
  };

  // ---- prologue: tile0's 4 units, then tile1's {Amh0, Bnh1} into buf1 ----
  GL(aP0lo, lds + dstT);                     GL(aP0hi, lds + 8192 + dstT);
  GL(bP1lo, lds + 49152 + dstT);             GL(bP1hi, lds + 49152 + 8192 + dstT);
  GL(bP0lo, lds + 32768 + dstT);             GL(bP0hi, lds + 32768 + 8192 + dstT);
  GL(aP1lo, lds + 16384 + dstT);             GL(aP1hi, lds + 16384 + 8192 + dstT);
  GL(aP0lo + 64, lds + 65536 + dstT);        GL(aP0hi + 64, lds + 65536 + 8192 + dstT);
  GL(bP1lo + 64, lds + 65536 + 49152 + dstT);
  GL(bP1hi + 64, lds + 65536 + 49152 + 8192 + dstT);
  WAITV4;   // retire tile0's 8 loads; tile1's {Am03,Bn23} stay in flight
  BARRIER;  // all waves' tile0 stages visible
  LDB0(lds);  // bg0 <- buf0.Bnh0 (tile0)
  // apply leads: P1/P2-staged units lead by 1 tile, P3/P4 units by 2 tiles
  bP0lo += 64;  bP0hi += 64;  aP1lo += 64;  aP1hi += 64;
  aP0lo += 128; aP0hi += 128; bP1lo += 128; bP1hi += 128;

  // ---- main loop: 2 tiles per iteration (compile-time buffer parity) ----
  for (int t = 0; t < NT; t += 2) {
    TILE_BODY(t, 0);
    TILE_BODY(t + 1, 1);
  }

  // ---- epilogue: C/D map col=lane&15, row=(lane>>4)*4+reg ----
  const int r0 = bm + wr * 128 + ((lane >> 4) << 2);
  const int c0 = bn + wc * 64 + (lane & 15);
  float bv[4];
#pragma unroll
  for (int n = 0; n < 4; ++n) bv[n] = bias[c0 + n * 16];
#pragma unroll
  for (int m = 0; m < 8; ++m) {
#pragma unroll
    for (int r = 0; r < 4; ++r) {
      float* crow = C + (size_t)(r0 + m * 16 + r) * N + c0;
#pragma unroll
      for (int n = 0; n < 4; ++n) crow[n * 16] = acc[m][n][r] + bv[n];
    }
  }
}

// ---------- fallback: fp32 tiled (odd shapes / tiny ws) ----------
__global__ void gemm_fallback_kernel(const float* __restrict__ X, const float* __restrict__ W,
                                     const float* __restrict__ scale, const float* __restrict__ bias,
                                     float* __restrict__ out, int M, int N, int K) {
  __shared__ float as[64][33];
  __shared__ float bs[64][33];
  int tx = threadIdx.x & 15, ty = threadIdx.x >> 4;
  int brow = blockIdx.y * 64, bcol = blockIdx.x * 64;
  float acc[4][4] = {};
  for (int k0 = 0; k0 < K; k0 += 32) {
    int kw = (K - k0 < 32) ? (K - k0) : 32;
    for (int i = 0; i < 8; ++i) {
      int idx = (int)threadIdx.x + i * 256;
      int r = idx >> 5, c = idx & 31;
      int ga = brow + r, gb = bcol + r;
      as[r][c] = (ga < M && c < kw) ? X[(size_t)ga * K + k0 + c] : 0.f;
      bs[r][c] = (gb < N && c < kw) ? W[(size_t)gb * K + k0 + c] * scale[gb] : 0.f;
    }
    __syncthreads();
    for (int k = 0; k < 32; ++k)
#pragma unroll
      for (int i = 0; i < 4; ++i)
#pragma unroll
        for (int j = 0; j < 4; ++j)
          acc[i][j] += as[ty * 4 + i][k] * bs[tx * 4 + j][k];
    __syncthreads();
  }
  for (int i = 0; i < 4; ++i) {
    int r = brow + ty * 4 + i;
    if (r >= M) continue;
    for (int j = 0; j < 4; ++j) {
      int c = bcol + tx * 4 + j;
      if (c < N) out[(size_t)r * N + c] = acc[i][j] + bias[c];
    }
  }
}

extern "C" void kernel_launch(void* const* d_in, const int* in_sizes, int n_in,
                              void* d_out, int out_size, void* d_ws, size_t ws_size,
                              hipStream_t stream) {
  const float* x     = (const float*)d_in[0];
  const float* w     = (const float*)d_in[1];
  const float* scale = (const float*)d_in[2];
  const float* bias  = (const float*)d_in[3];
  float* out = (float*)d_out;

  const long N = in_sizes[2];            // D_OUT
  const long K = in_sizes[1] / N;        // D_IN
  const long M = (long)in_sizes[0] / K;  // B*S

  const size_t need = ((size_t)M * K + (size_t)N * K) * sizeof(unsigned short);
  const long NT = K / 64;
  const bool ok = (ws_size >= need) && (M % 256 == 0) && (N % 256 == 0) &&
                  (K % 128 == 0) && (NT >= 4);

  if (ok) {
    unsigned short* xa = (unsigned short*)d_ws;
    unsigned short* wb = xa + (size_t)M * K;
    int n8x = (int)((size_t)M * K / 8);
    int n8w = (int)((size_t)N * K / 8);
    cvt_xw_kernel<<<2048, 256, 0, stream>>>(x, w, scale, (ushort8*)xa, (ushort8*)wb,
                                            n8x, n8w, (int)(K / 8));

    (void)hipFuncSetAttribute((const void*)gemm256_8ph,
                              hipFuncAttributeMaxDynamicSharedMemorySize, 131072);
    int nwg = (int)((M / 256) * (N / 256));
    gemm256_8ph<<<nwg, 512, 131072, stream>>>(xa, wb, bias, out, (int)M, (int)N, (int)K);
  } else {
    dim3 grid((unsigned)((N + 63) / 64), (unsigned)((M + 63) / 64));
    gemm_fallback_kernel<<<grid, 256, 0, stream>>>(x, w, scale, bias, out, (int)M, (int)N, (int)K);
  }
}